// Round 6
// baseline (507.004 us; speedup 1.0000x reference)
//
#include <hip/hip_runtime.h>
#include <hip/hip_fp16.h>

#define D 128
#define EDGE_IN 258
#define TI 32

__device__ __forceinline__ float rl_f(float v, int j) {
  return __int_as_float(__builtin_amdgcn_readlane(__float_as_int(v), j));
}
__device__ __forceinline__ int rl_i(int v, int j) {
  return __builtin_amdgcn_readlane(v, j);
}
__device__ __forceinline__ float dot4(float4 a, float4 b) {
  return a.x * b.x + a.y * b.y + a.z * b.z + a.w * b.w;
}

// ---------------- CSR build ----------------
__global__ void zero_int(int* __restrict__ p, int n) {
  int i = blockIdx.x * blockDim.x + threadIdx.x;
  if (i < n) p[i] = 0;
}

__global__ void hist_kernel(const int* __restrict__ dst, int* __restrict__ deg, int ne) {
  int e = blockIdx.x * blockDim.x + threadIdx.x;
  if (e < ne) atomicAdd(&deg[dst[e]], 1);
}

// hierarchical scan: stage 1 — per-block (1024-elem chunk) sums
__global__ __launch_bounds__(256) void scan_part(const int* __restrict__ deg,
                                                 int* __restrict__ bsum, int n) {
  __shared__ int red[256];
  int b = blockIdx.x, tid = threadIdx.x;
  int base = b * 1024 + tid * 4;
  int s = 0;
#pragma unroll
  for (int j = 0; j < 4; j++) { int idx = base + j; if (idx < n) s += deg[idx]; }
  red[tid] = s;
  __syncthreads();
  for (int off = 128; off; off >>= 1) {
    if (tid < off) red[tid] += red[tid + off];
    __syncthreads();
  }
  if (tid == 0) bsum[b] = red[0];
}

// stage 2 — scan the block sums (nb <= 256) in one small block
__global__ __launch_bounds__(256) void scan_bsums(int* __restrict__ bsum, int nb) {
  __shared__ int part[256];
  int tid = threadIdx.x;
  int v = (tid < nb) ? bsum[tid] : 0;
  part[tid] = v;
  __syncthreads();
  for (int off = 1; off < 256; off <<= 1) {
    int t = (tid >= off) ? part[tid - off] : 0;
    __syncthreads();
    part[tid] += t;
    __syncthreads();
  }
  if (tid < nb) bsum[tid] = (tid == 0) ? 0 : part[tid - 1];  // exclusive
}

// stage 3 — per-block rescan + global offset; writes offs and cur
__global__ __launch_bounds__(256) void scan_final(const int* __restrict__ deg,
                                                  const int* __restrict__ bsumex,
                                                  int* __restrict__ offs,
                                                  int* __restrict__ cur, int n, int ne) {
  __shared__ int part[256];
  int b = blockIdx.x, tid = threadIdx.x;
  int base = b * 1024 + tid * 4;
  int v[4];
  int s = 0;
#pragma unroll
  for (int j = 0; j < 4; j++) {
    int idx = base + j;
    v[j] = (idx < n) ? deg[idx] : 0;
    s += v[j];
  }
  part[tid] = s;
  __syncthreads();
  for (int off = 1; off < 256; off <<= 1) {
    int t = (tid >= off) ? part[tid - off] : 0;
    __syncthreads();
    part[tid] += t;
    __syncthreads();
  }
  int run = bsumex[b] + ((tid == 0) ? 0 : part[tid - 1]);
#pragma unroll
  for (int j = 0; j < 4; j++) {
    int idx = base + j;
    if (idx < n) { offs[idx] = run; cur[idx] = run; run += v[j]; }
  }
  if (b == 0 && tid == 0) offs[n] = ne;
}

// pre-gather edge metadata into CSR slot order: meta[p] = {src, rx, ry, -}
__global__ void scatter_kernel(const int* __restrict__ dst, const int* __restrict__ srcIdx,
                               const float2* __restrict__ rel, int* __restrict__ cur,
                               float4* __restrict__ meta, int ne) {
  int e = blockIdx.x * blockDim.x + threadIdx.x;
  if (e < ne) {
    int p = atomicAdd(&cur[dst[e]], 1);
    float2 r = rel[e];
    meta[p] = make_float4(__int_as_float(srcIdx[e]), r.x, r.y, 0.f);
  }
}

// ---------------- weight prep ----------------
// WT (float4 view): [L][2(src,dst)][32(k4)][128(d)], float4 holds k..k+3
// Wrel: [L][2][128]   WattA: [L][2][128] (16B-aligned repack of W_att)
__global__ void transpose_kernel(const float* __restrict__ W_emb,
                                 const float* __restrict__ W_att,
                                 float* __restrict__ WT, float* __restrict__ Wrel,
                                 float* __restrict__ WattA) {
  int d = threadIdx.x;      // 0..127
  int k = blockIdx.x;       // 0..127
  int part = blockIdx.y;    // 0,1 = src/dst emb ; 2 = rel emb cols ; 3,4 = att src/dst
  int l = blockIdx.z;
  if (part < 2) {
    int off = part ? 130 : 0;
    int mat = l * 2 + part;
    WT[((mat * 32 + (k >> 2)) * 128 + d) * 4 + (k & 3)] =
        W_emb[(size_t)(l * D + d) * EDGE_IN + off + k];
  } else if (part == 2) {
    if (k < 2) Wrel[(l * 2 + k) * 128 + d] = W_emb[(size_t)(l * D + d) * EDGE_IN + 128 + k];
  } else if (k == 0) {
    int off = (part == 3) ? 0 : 130;
    WattA[(l * 2 + (part - 3)) * 128 + d] = W_att[(size_t)l * EDGE_IN + off + d];
  }
}

// ---------------- fused per-actor projections + attention dots ----------------
// Thread tiling: 4 actors x 4 dims -> 4x fewer LDS reads than 16x1 (LDS pipe was
// the bottleneck: 512 ds_read_b128/thread ~62us of LDS time vs 21us FMA floor).
__global__ __launch_bounds__(256) void proj_kernel(const float* __restrict__ feat,
                                                   const float4* __restrict__ WT,
                                                   const float* __restrict__ WattA,
                                                   __half* __restrict__ Ps16,
                                                   float* __restrict__ Pd,
                                                   float* __restrict__ a_s,
                                                   float* __restrict__ a_d, int n, int l) {
  __shared__ float lf[TI][D];  // 16 KB
  int i0 = blockIdx.x * TI;
  int tid = threadIdx.x;
  for (int t = tid; t < TI * D / 4; t += 256) {
    int fi = t >> 5;
    int gi = i0 + fi;
    float4 v = (gi < n) ? ((const float4*)feat)[(size_t)gi * (D / 4) + (t & 31)]
                        : make_float4(0.f, 0.f, 0.f, 0.f);
    ((float4*)&lf[0][0])[t] = v;
  }
  __syncthreads();
  int dg = tid & 31;  // dim group: dims 4dg..4dg+3
  int ag = tid >> 5;  // actor group: actors 4ag..4ag+3
  const float4* Ws = WT + (size_t)(l * 2 + 0) * 32 * 128;
  const float4* Wd = WT + (size_t)(l * 2 + 1) * 32 * 128;
  float accs[4][4], accd[4][4];
#pragma unroll
  for (int a = 0; a < 4; a++)
#pragma unroll
    for (int dd = 0; dd < 4; dd++) { accs[a][dd] = 0.f; accd[a][dd] = 0.f; }

  for (int k4 = 0; k4 < 32; k4++) {
    float4 fa[4], wsv[4], wdv[4];
#pragma unroll
    for (int a = 0; a < 4; a++) fa[a] = *(const float4*)&lf[4 * ag + a][k4 * 4];
#pragma unroll
    for (int dd = 0; dd < 4; dd++) {
      wsv[dd] = Ws[k4 * 128 + 4 * dg + dd];
      wdv[dd] = Wd[k4 * 128 + 4 * dg + dd];
    }
#pragma unroll
    for (int a = 0; a < 4; a++)
#pragma unroll
      for (int dd = 0; dd < 4; dd++) {
        accs[a][dd] += dot4(fa[a], wsv[dd]);
        accd[a][dd] += dot4(fa[a], wdv[dd]);
      }
  }

  // attention dots: each dim-group lane covers k-chunk k4==dg, then reduce over 32 lanes
  float sa[4], ta[4];
  {
    float4 was = *(const float4*)&WattA[(size_t)(l * 2 + 0) * 128 + 4 * dg];
    float4 wat = *(const float4*)&WattA[(size_t)(l * 2 + 1) * 128 + 4 * dg];
#pragma unroll
    for (int a = 0; a < 4; a++) {
      float4 f = *(const float4*)&lf[4 * ag + a][4 * dg];
      sa[a] = dot4(f, was);
      ta[a] = dot4(f, wat);
    }
#pragma unroll
    for (int o = 1; o < 32; o <<= 1) {
#pragma unroll
      for (int a = 0; a < 4; a++) {
        sa[a] += __shfl_xor(sa[a], o, 64);
        ta[a] += __shfl_xor(ta[a], o, 64);
      }
    }
  }

#pragma unroll
  for (int a = 0; a < 4; a++) {
    int gi = i0 + 4 * ag + a;
    if (gi < n) {
      ushort4 u;
      u.x = __half_as_ushort(__float2half(accs[a][0]));
      u.y = __half_as_ushort(__float2half(accs[a][1]));
      u.z = __half_as_ushort(__float2half(accs[a][2]));
      u.w = __half_as_ushort(__float2half(accs[a][3]));
      *(ushort4*)&Ps16[(size_t)gi * D + 4 * dg] = u;
      *(float4*)&Pd[(size_t)gi * D + 4 * dg] =
          make_float4(accd[a][0], accd[a][1], accd[a][2], accd[a][3]);
      if (dg == 0) { a_s[gi] = sa[a]; a_d[gi] = ta[a]; }
    }
  }
}

// ---------------- edge pass: one wave per dst ----------------
// Phase A: lane-parallel scores, wave-reduced softmax.
// Phase B: 8-deep independent Ps gathers (VGPR=16 before -> huge headroom; avg
// degree 16 means one chunk of 16 edges -> two 8-batches fully overlap latency).
__global__ __launch_bounds__(256) void edge_kernel(
    const __half2* __restrict__ Ps, const float* __restrict__ Pd,
    const float* __restrict__ a_s, const float* __restrict__ a_d,
    const float4* __restrict__ meta, const int* __restrict__ offs,
    const float* __restrict__ Wrel, const float* __restrict__ W_att,
    float* __restrict__ out, int n, int l) {
  int wid = (blockIdx.x * blockDim.x + threadIdx.x) >> 6;
  if (wid >= n) return;
  int lane = threadIdx.x & 63;
  int d0 = 2 * lane;
  const float2 wc0 = *(const float2*)&Wrel[(l * 2 + 0) * 128 + d0];
  const float2 wc1 = *(const float2*)&Wrel[(l * 2 + 1) * 128 + d0];
  float wax = W_att[(size_t)l * EDGE_IN + 128];
  float way = W_att[(size_t)l * EDGE_IN + 129];
  float ad = a_d[wid];
  int p0 = offs[wid], p1 = offs[wid + 1];
  float m = -1e30f, lsum = 0.f;
  float accx = 0.f, accy = 0.f;
  for (int c0 = p0; c0 < p1; c0 += 64) {
    int cn = min(64, p1 - c0);
    int si = 0;
    float rx = 0.f, ry = 0.f, s = -1e30f;
    if (lane < cn) {
      float4 mt = meta[c0 + lane];
      si = __float_as_int(mt.x);
      rx = mt.y;
      ry = mt.z;
      float sc = a_s[si] + ad + rx * wax + ry * way;
      s = (sc > 0.f) ? sc : 0.2f * sc;
    }
    float cm = s;
#pragma unroll
    for (int o = 32; o; o >>= 1) cm = fmaxf(cm, __shfl_xor(cm, o, 64));
    float mnew = fmaxf(m, cm);
    float corrOld = __expf(m - mnew);
    float w = (lane < cn) ? __expf(s - mnew) : 0.f;
    float csum = w;
#pragma unroll
    for (int o = 32; o; o >>= 1) csum += __shfl_xor(csum, o, 64);
    lsum = lsum * corrOld + csum;
    accx *= corrOld;
    accy *= corrOld;
    m = mnew;
    int j = 0;
    for (; j + 8 <= cn; j += 8) {
      float2 f[8];
      float wj[8], xj[8], yj[8];
#pragma unroll
      for (int q = 0; q < 8; q++) {
        int sj = rl_i(si, j + q);
        wj[q] = rl_f(w, j + q);
        xj[q] = rl_f(rx, j + q);
        yj[q] = rl_f(ry, j + q);
        f[q] = __half22float2(Ps[(size_t)sj * 64 + lane]);
      }
#pragma unroll
      for (int q = 0; q < 8; q++) {
        accx += wj[q] * (f[q].x + xj[q] * wc0.x + yj[q] * wc1.x);
        accy += wj[q] * (f[q].y + xj[q] * wc0.y + yj[q] * wc1.y);
      }
    }
    if (j < cn) {
      float2 f[8];
      float wj[8], xj[8], yj[8];
      int r = cn - j;  // 1..7
#pragma unroll
      for (int q = 0; q < 8; q++) {
        if (q < r) {
          int sj = rl_i(si, j + q);
          wj[q] = rl_f(w, j + q);
          xj[q] = rl_f(rx, j + q);
          yj[q] = rl_f(ry, j + q);
          f[q] = __half22float2(Ps[(size_t)sj * 64 + lane]);
        }
      }
#pragma unroll
      for (int q = 0; q < 8; q++) {
        if (q < r) {
          accx += wj[q] * (f[q].x + xj[q] * wc0.x + yj[q] * wc1.x);
          accy += wj[q] * (f[q].y + xj[q] * wc0.y + yj[q] * wc1.y);
        }
      }
    }
  }
  float2 o2 = make_float2(0.f, 0.f);
  if (p1 > p0) {
    float inv = 1.0f / lsum;
    float2 pd = *(const float2*)&Pd[(size_t)wid * D + d0];
    o2.x = fmaxf(accx * inv + pd.x, 0.f);
    o2.y = fmaxf(accy * inv + pd.y, 0.f);
  }
  *(float2*)&out[(size_t)wid * D + d0] = o2;
}

extern "C" void kernel_launch(void* const* d_in, const int* in_sizes, int n_in,
                              void* d_out, int out_size, void* d_ws, size_t ws_size,
                              hipStream_t stream) {
  const float* actor = (const float*)d_in[0];
  const float* rel   = (const float*)d_in[1];
  const float* W_att = (const float*)d_in[2];
  const float* W_emb = (const float*)d_in[3];
  const int* srcIdx  = (const int*)d_in[4];
  const int* dstIdx  = (const int*)d_in[5];
  int n  = in_sizes[0] / D;          // 50000
  int ne = in_sizes[4];              // 800000
  int Lnum = in_sizes[2] / EDGE_IN;  // 2
  float* fout_last = (float*)d_out;

  // workspace carve-up (meta first for 16B alignment)
  float* ws = (float*)d_ws;
  size_t o = 0;
  float4* meta = (float4*)ws; o += 4 * (size_t)ne;
  float* WT  = ws + o; o += (size_t)Lnum * 2 * 128 * 128;
  float* Wre = ws + o; o += (size_t)Lnum * 2 * 128;
  float* WattA = ws + o; o += (size_t)Lnum * 2 * 128;
  float* Pd  = ws + o; o += (size_t)n * D;
  float* a_s = ws + o; o += (size_t)n + 64;
  float* a_d = ws + o; o += (size_t)n + 64;
  __half* Ps16 = (__half*)(ws + o); o += (size_t)n * D / 2;
  int* ibuf = (int*)(ws + o);
  size_t io = 0;
  int* deg  = ibuf + io; io += n + 64;
  int* offs = ibuf + io; io += n + 64;
  int* cur  = ibuf + io; io += n + 64;
  int* bsum = ibuf + io; io += 256;

  int nb = (n + 1023) / 1024;  // chunk-blocks for the scan

  // --- CSR by dst with pre-gathered per-edge metadata ---
  zero_int<<<(n + 255) / 256, 256, 0, stream>>>(deg, n);
  hist_kernel<<<(ne + 255) / 256, 256, 0, stream>>>(dstIdx, deg, ne);
  scan_part<<<nb, 256, 0, stream>>>(deg, bsum, n);
  scan_bsums<<<1, 256, 0, stream>>>(bsum, nb);
  scan_final<<<nb, 256, 0, stream>>>(deg, bsum, offs, cur, n, ne);
  scatter_kernel<<<(ne + 255) / 256, 256, 0, stream>>>(dstIdx, srcIdx, (const float2*)rel,
                                                       cur, meta, ne);
  transpose_kernel<<<dim3(128, 5, Lnum), 128, 0, stream>>>(W_emb, W_att, WT, Wre, WattA);

  // --- layers; d_out doubles as the intermediate feature buffer ---
  const float* fin = actor;
  for (int l = 0; l < Lnum; l++) {
    proj_kernel<<<(n + TI - 1) / TI, 256, 0, stream>>>(fin, (const float4*)WT, WattA,
                                                       Ps16, Pd, a_s, a_d, n, l);
    edge_kernel<<<(n + 3) / 4, 256, 0, stream>>>((const __half2*)Ps16, Pd, a_s, a_d, meta,
                                                 offs, Wre, W_att, fout_last, n, l);
    fin = fout_last;
  }
}

// Round 8
// 419.521 us; speedup vs baseline: 1.2085x; 1.2085x over previous
//
#include <hip/hip_runtime.h>
#include <hip/hip_fp16.h>

#define D 128
#define EDGE_IN 258
#define TI 32

__device__ __forceinline__ float rl_f(float v, int j) {
  return __int_as_float(__builtin_amdgcn_readlane(__float_as_int(v), j));
}
__device__ __forceinline__ int rl_i(int v, int j) {
  return __builtin_amdgcn_readlane(v, j);
}
__device__ __forceinline__ float dot4(float4 a, float4 b) {
  return a.x * b.x + a.y * b.y + a.z * b.z + a.w * b.w;
}

// ---------------- CSR build ----------------
__global__ void zero_int(int* __restrict__ p, int n) {
  int i = blockIdx.x * blockDim.x + threadIdx.x;
  if (i < n) p[i] = 0;
}

__global__ void hist_kernel(const int* __restrict__ dst, int* __restrict__ deg, int ne) {
  int e = blockIdx.x * blockDim.x + threadIdx.x;
  if (e < ne) atomicAdd(&deg[dst[e]], 1);
}

// hierarchical scan: stage 1 — per-block (1024-elem chunk) sums
__global__ __launch_bounds__(256) void scan_part(const int* __restrict__ deg,
                                                 int* __restrict__ bsum, int n) {
  __shared__ int red[256];
  int b = blockIdx.x, tid = threadIdx.x;
  int base = b * 1024 + tid * 4;
  int s = 0;
#pragma unroll
  for (int j = 0; j < 4; j++) { int idx = base + j; if (idx < n) s += deg[idx]; }
  red[tid] = s;
  __syncthreads();
  for (int off = 128; off; off >>= 1) {
    if (tid < off) red[tid] += red[tid + off];
    __syncthreads();
  }
  if (tid == 0) bsum[b] = red[0];
}

// stage 2 — scan the block sums (nb <= 256) in one small block
__global__ __launch_bounds__(256) void scan_bsums(int* __restrict__ bsum, int nb) {
  __shared__ int part[256];
  int tid = threadIdx.x;
  int v = (tid < nb) ? bsum[tid] : 0;
  part[tid] = v;
  __syncthreads();
  for (int off = 1; off < 256; off <<= 1) {
    int t = (tid >= off) ? part[tid - off] : 0;
    __syncthreads();
    part[tid] += t;
    __syncthreads();
  }
  if (tid < nb) bsum[tid] = (tid == 0) ? 0 : part[tid - 1];  // exclusive
}

// stage 3 — per-block rescan + global offset; writes offs and cur
__global__ __launch_bounds__(256) void scan_final(const int* __restrict__ deg,
                                                  const int* __restrict__ bsumex,
                                                  int* __restrict__ offs,
                                                  int* __restrict__ cur, int n, int ne) {
  __shared__ int part[256];
  int b = blockIdx.x, tid = threadIdx.x;
  int base = b * 1024 + tid * 4;
  int v[4];
  int s = 0;
#pragma unroll
  for (int j = 0; j < 4; j++) {
    int idx = base + j;
    v[j] = (idx < n) ? deg[idx] : 0;
    s += v[j];
  }
  part[tid] = s;
  __syncthreads();
  for (int off = 1; off < 256; off <<= 1) {
    int t = (tid >= off) ? part[tid - off] : 0;
    __syncthreads();
    part[tid] += t;
    __syncthreads();
  }
  int run = bsumex[b] + ((tid == 0) ? 0 : part[tid - 1]);
#pragma unroll
  for (int j = 0; j < 4; j++) {
    int idx = base + j;
    if (idx < n) { offs[idx] = run; cur[idx] = run; run += v[j]; }
  }
  if (b == 0 && tid == 0) offs[n] = ne;
}

// pre-gather edge metadata into CSR slot order: meta[p] = {src, rx, ry, -}
__global__ void scatter_kernel(const int* __restrict__ dst, const int* __restrict__ srcIdx,
                               const float2* __restrict__ rel, int* __restrict__ cur,
                               float4* __restrict__ meta, int ne) {
  int e = blockIdx.x * blockDim.x + threadIdx.x;
  if (e < ne) {
    int p = atomicAdd(&cur[dst[e]], 1);
    float2 r = rel[e];
    meta[p] = make_float4(__int_as_float(srcIdx[e]), r.x, r.y, 0.f);
  }
}

// ---------------- weight prep ----------------
// WT (float4 view): [L][2(src,dst)][32(k4)][128(d)], float4 holds k..k+3
// Wrel: [L][2][128]   WattA: [L][2][128] (16B-aligned repack of W_att)
__global__ void transpose_kernel(const float* __restrict__ W_emb,
                                 const float* __restrict__ W_att,
                                 float* __restrict__ WT, float* __restrict__ Wrel,
                                 float* __restrict__ WattA) {
  int d = threadIdx.x;      // 0..127
  int k = blockIdx.x;       // 0..127
  int part = blockIdx.y;    // 0,1 = src/dst emb ; 2 = rel emb cols ; 3,4 = att src/dst
  int l = blockIdx.z;
  if (part < 2) {
    int off = part ? 130 : 0;
    int mat = l * 2 + part;
    WT[((mat * 32 + (k >> 2)) * 128 + d) * 4 + (k & 3)] =
        W_emb[(size_t)(l * D + d) * EDGE_IN + off + k];
  } else if (part == 2) {
    if (k < 2) Wrel[(l * 2 + k) * 128 + d] = W_emb[(size_t)(l * D + d) * EDGE_IN + 128 + k];
  } else if (k == 0) {
    int off = (part == 3) ? 0 : 130;
    WattA[(l * 2 + (part - 3)) * 128 + d] = W_att[(size_t)l * EDGE_IN + off + d];
  }
}

// ---------------- fused per-actor projections + attention dots ----------------
// 4 actors x 4 STRIDED dims per thread (d = dg+32j, dg=tid&31):
//  - weight loads Ws[k4*128 + dg + 32j]: lanes 0..31 read 32 consecutive float4
//    (512B contiguous, half-wave broadcast) -> coalesced. (R6 regression: the
//    consecutive-dim variant read stride-64B -> 2KB L2 lines per instr, 122us.)
//  - feat LDS reads: half-wave broadcast (2 addrs/instr), conflict-free.
__global__ __launch_bounds__(256) void proj_kernel(const float* __restrict__ feat,
                                                   const float4* __restrict__ WT,
                                                   const float* __restrict__ WattA,
                                                   __half* __restrict__ Ps16,
                                                   float* __restrict__ Pd,
                                                   float* __restrict__ a_s,
                                                   float* __restrict__ a_d, int n, int l) {
  __shared__ float lf[TI][D];  // 16 KB
  int i0 = blockIdx.x * TI;
  int tid = threadIdx.x;
  for (int t = tid; t < TI * D / 4; t += 256) {
    int fi = t >> 5;
    int gi = i0 + fi;
    float4 v = (gi < n) ? ((const float4*)feat)[(size_t)gi * (D / 4) + (t & 31)]
                        : make_float4(0.f, 0.f, 0.f, 0.f);
    ((float4*)&lf[0][0])[t] = v;
  }
  __syncthreads();
  int dg = tid & 31;  // dims dg, dg+32, dg+64, dg+96
  int ag = tid >> 5;  // actors 4ag..4ag+3
  const float4* Ws = WT + (size_t)(l * 2 + 0) * 32 * 128;
  const float4* Wd = WT + (size_t)(l * 2 + 1) * 32 * 128;
  float accs[4][4], accd[4][4];  // [actor][dim j]
#pragma unroll
  for (int a = 0; a < 4; a++)
#pragma unroll
    for (int j = 0; j < 4; j++) { accs[a][j] = 0.f; accd[a][j] = 0.f; }

  for (int k4 = 0; k4 < 32; k4++) {
    float4 fa[4], wsv[4], wdv[4];
#pragma unroll
    for (int a = 0; a < 4; a++) fa[a] = *(const float4*)&lf[4 * ag + a][k4 * 4];
#pragma unroll
    for (int j = 0; j < 4; j++) {
      wsv[j] = Ws[k4 * 128 + dg + 32 * j];  // coalesced: 32 consecutive float4
      wdv[j] = Wd[k4 * 128 + dg + 32 * j];
    }
#pragma unroll
    for (int a = 0; a < 4; a++)
#pragma unroll
      for (int j = 0; j < 4; j++) {
        accs[a][j] += dot4(fa[a], wsv[j]);
        accd[a][j] += dot4(fa[a], wdv[j]);
      }
  }

  // attention dots: each dim-group lane covers k-chunk k4==dg, then reduce over 32 lanes
  float sa[4], ta[4];
  {
    float4 was = *(const float4*)&WattA[(size_t)(l * 2 + 0) * 128 + 4 * dg];
    float4 wat = *(const float4*)&WattA[(size_t)(l * 2 + 1) * 128 + 4 * dg];
#pragma unroll
    for (int a = 0; a < 4; a++) {
      float4 f = *(const float4*)&lf[4 * ag + a][4 * dg];
      sa[a] = dot4(f, was);
      ta[a] = dot4(f, wat);
    }
#pragma unroll
    for (int o = 1; o < 32; o <<= 1) {
#pragma unroll
      for (int a = 0; a < 4; a++) {
        sa[a] += __shfl_xor(sa[a], o, 64);
        ta[a] += __shfl_xor(ta[a], o, 64);
      }
    }
  }

#pragma unroll
  for (int a = 0; a < 4; a++) {
    int gi = i0 + 4 * ag + a;
    if (gi < n) {
#pragma unroll
      for (int j = 0; j < 4; j++) {
        Ps16[(size_t)gi * D + dg + 32 * j] = __float2half(accs[a][j]);
        Pd[(size_t)gi * D + dg + 32 * j] = accd[a][j];
      }
      if (dg == 0) { a_s[gi] = sa[a]; a_d[gi] = ta[a]; }
    }
  }
}

// ---------------- edge pass: one wave per dst ----------------
// Phase A: lane-parallel scores, wave-reduced softmax.
// Phase B: 8-deep independent Ps gathers.
__global__ __launch_bounds__(256) void edge_kernel(
    const __half2* __restrict__ Ps, const float* __restrict__ Pd,
    const float* __restrict__ a_s, const float* __restrict__ a_d,
    const float4* __restrict__ meta, const int* __restrict__ offs,
    const float* __restrict__ Wrel, const float* __restrict__ W_att,
    float* __restrict__ out, int n, int l) {
  int wid = (blockIdx.x * blockDim.x + threadIdx.x) >> 6;
  if (wid >= n) return;
  int lane = threadIdx.x & 63;
  int d0 = 2 * lane;
  const float2 wc0 = *(const float2*)&Wrel[(l * 2 + 0) * 128 + d0];
  const float2 wc1 = *(const float2*)&Wrel[(l * 2 + 1) * 128 + d0];
  float wax = W_att[(size_t)l * EDGE_IN + 128];
  float way = W_att[(size_t)l * EDGE_IN + 129];
  float ad = a_d[wid];
  int p0 = offs[wid], p1 = offs[wid + 1];
  float m = -1e30f, lsum = 0.f;
  float accx = 0.f, accy = 0.f;
  for (int c0 = p0; c0 < p1; c0 += 64) {
    int cn = min(64, p1 - c0);
    int si = 0;
    float rx = 0.f, ry = 0.f, s = -1e30f;
    if (lane < cn) {
      float4 mt = meta[c0 + lane];
      si = __float_as_int(mt.x);
      rx = mt.y;
      ry = mt.z;
      float sc = a_s[si] + ad + rx * wax + ry * way;
      s = (sc > 0.f) ? sc : 0.2f * sc;
    }
    float cm = s;
#pragma unroll
    for (int o = 32; o; o >>= 1) cm = fmaxf(cm, __shfl_xor(cm, o, 64));
    float mnew = fmaxf(m, cm);
    float corrOld = __expf(m - mnew);
    float w = (lane < cn) ? __expf(s - mnew) : 0.f;
    float csum = w;
#pragma unroll
    for (int o = 32; o; o >>= 1) csum += __shfl_xor(csum, o, 64);
    lsum = lsum * corrOld + csum;
    accx *= corrOld;
    accy *= corrOld;
    m = mnew;
    int j = 0;
    for (; j + 8 <= cn; j += 8) {
      float2 f[8];
      float wj[8], xj[8], yj[8];
#pragma unroll
      for (int q = 0; q < 8; q++) {
        int sj = rl_i(si, j + q);
        wj[q] = rl_f(w, j + q);
        xj[q] = rl_f(rx, j + q);
        yj[q] = rl_f(ry, j + q);
        f[q] = __half22float2(Ps[(size_t)sj * 64 + lane]);
      }
#pragma unroll
      for (int q = 0; q < 8; q++) {
        accx += wj[q] * (f[q].x + xj[q] * wc0.x + yj[q] * wc1.x);
        accy += wj[q] * (f[q].y + xj[q] * wc0.y + yj[q] * wc1.y);
      }
    }
    if (j < cn) {
      float2 f[8];
      float wj[8], xj[8], yj[8];
      int r = cn - j;  // 1..7
#pragma unroll
      for (int q = 0; q < 8; q++) {
        if (q < r) {
          int sj = rl_i(si, j + q);
          wj[q] = rl_f(w, j + q);
          xj[q] = rl_f(rx, j + q);
          yj[q] = rl_f(ry, j + q);
          f[q] = __half22float2(Ps[(size_t)sj * 64 + lane]);
        }
      }
#pragma unroll
      for (int q = 0; q < 8; q++) {
        if (q < r) {
          accx += wj[q] * (f[q].x + xj[q] * wc0.x + yj[q] * wc1.x);
          accy += wj[q] * (f[q].y + xj[q] * wc0.y + yj[q] * wc1.y);
        }
      }
    }
  }
  float2 o2 = make_float2(0.f, 0.f);
  if (p1 > p0) {
    float inv = 1.0f / lsum;
    float2 pd = *(const float2*)&Pd[(size_t)wid * D + d0];
    o2.x = fmaxf(accx * inv + pd.x, 0.f);
    o2.y = fmaxf(accy * inv + pd.y, 0.f);
  }
  *(float2*)&out[(size_t)wid * D + d0] = o2;
}

extern "C" void kernel_launch(void* const* d_in, const int* in_sizes, int n_in,
                              void* d_out, int out_size, void* d_ws, size_t ws_size,
                              hipStream_t stream) {
  const float* actor = (const float*)d_in[0];
  const float* rel   = (const float*)d_in[1];
  const float* W_att = (const float*)d_in[2];
  const float* W_emb = (const float*)d_in[3];
  const int* srcIdx  = (const int*)d_in[4];
  const int* dstIdx  = (const int*)d_in[5];
  int n  = in_sizes[0] / D;          // 50000
  int ne = in_sizes[4];              // 800000
  int Lnum = in_sizes[2] / EDGE_IN;  // 2
  float* fout_last = (float*)d_out;

  // workspace carve-up (meta first for 16B alignment)
  float* ws = (float*)d_ws;
  size_t o = 0;
  float4* meta = (float4*)ws; o += 4 * (size_t)ne;
  float* WT  = ws + o; o += (size_t)Lnum * 2 * 128 * 128;
  float* Wre = ws + o; o += (size_t)Lnum * 2 * 128;
  float* WattA = ws + o; o += (size_t)Lnum * 2 * 128;
  float* Pd  = ws + o; o += (size_t)n * D;
  float* a_s = ws + o; o += (size_t)n + 64;
  float* a_d = ws + o; o += (size_t)n + 64;
  __half* Ps16 = (__half*)(ws + o); o += (size_t)n * D / 2;
  int* ibuf = (int*)(ws + o);
  size_t io = 0;
  int* deg  = ibuf + io; io += n + 64;
  int* offs = ibuf + io; io += n + 64;
  int* cur  = ibuf + io; io += n + 64;
  int* bsum = ibuf + io; io += 256;

  int nb = (n + 1023) / 1024;  // chunk-blocks for the scan

  // --- CSR by dst with pre-gathered per-edge metadata ---
  zero_int<<<(n + 255) / 256, 256, 0, stream>>>(deg, n);
  hist_kernel<<<(ne + 255) / 256, 256, 0, stream>>>(dstIdx, deg, ne);
  scan_part<<<nb, 256, 0, stream>>>(deg, bsum, n);
  scan_bsums<<<1, 256, 0, stream>>>(bsum, nb);
  scan_final<<<nb, 256, 0, stream>>>(deg, bsum, offs, cur, n, ne);
  scatter_kernel<<<(ne + 255) / 256, 256, 0, stream>>>(dstIdx, srcIdx, (const float2*)rel,
                                                       cur, meta, ne);
  transpose_kernel<<<dim3(128, 5, Lnum), 128, 0, stream>>>(W_emb, W_att, WT, Wre, WattA);

  // --- layers; d_out doubles as the intermediate feature buffer ---
  const float* fin = actor;
  for (int l = 0; l < Lnum; l++) {
    proj_kernel<<<(n + TI - 1) / TI, 256, 0, stream>>>(fin, (const float4*)WT, WattA,
                                                       Ps16, Pd, a_s, a_d, n, l);
    edge_kernel<<<(n + 3) / 4, 256, 0, stream>>>((const __half2*)Ps16, Pd, a_s, a_d, meta,
                                                 offs, Wre, W_att, fout_last, n, l);
    fin = fout_last;
  }
}